// Round 6
// baseline (294.446 us; speedup 1.0000x reference)
//
#include <hip/hip_runtime.h>
#include <math.h>

#define SEQ  2048
#define NHD  16
#define HD   64
#define HDIM 1024

typedef short s16x8 __attribute__((ext_vector_type(8)));   // 8 x bf16 (4 VGPRs)
typedef short s16x4 __attribute__((ext_vector_type(4)));
typedef float f32x4 __attribute__((ext_vector_type(4)));

typedef const __attribute__((address_space(1))) unsigned int* gp_t;
typedef __attribute__((address_space(3))) unsigned int* lp_t;

__device__ __forceinline__ void async16(const short* g, short* l) {
    // 16B per lane, LDS dest = wave-uniform base + lane*16
    __builtin_amdgcn_global_load_lds((gp_t)g, (lp_t)l, 16, 0, 0);
}

__device__ __forceinline__ short f2bf(float f) {   // RNE f32 -> bf16 bits
    unsigned int u = __float_as_uint(f);
    u += 0x7fff + ((u >> 16) & 1);
    return (short)(u >> 16);
}

// ---------------- input dtype detector (keep: free insurance) ----------------
__global__ void detect_k(const unsigned short* __restrict__ x, int* __restrict__ flag) {
    int cnt = 0;
    #pragma unroll 4
    for (int j = 0; j < 32; ++j) {
        unsigned short h = x[threadIdx.x * 32 + j];
        int e = (h >> 7) & 0xFF;
        cnt += (e >= 100 && e <= 140) ? 1 : 0;
    }
    __shared__ int tot;
    if (threadIdx.x == 0) tot = 0;
    __syncthreads();
    atomicAdd(&tot, cnt);
    __syncthreads();
    if (threadIdx.x == 0) *flag = (tot > (8192 * 9) / 10) ? 1 : 0;
}

// ---------------- convert input -> canonical bf16 ----------------------------
__global__ void cvt_k(const void* __restrict__ in, short* __restrict__ out,
                      const int* __restrict__ flag, int n4) {
    int i = blockIdx.x * 256 + threadIdx.x;
    if (i >= n4) return;
    if (*flag) {                               // already bf16: straight copy
        ((s16x4*)out)[i] = ((const s16x4*)in)[i];
    } else {                                   // f32 -> bf16 RNE
        f32x4 v = ((const f32x4*)in)[i];
        s16x4 r;
        r[0] = f2bf(v[0]); r[1] = f2bf(v[1]);
        r[2] = f2bf(v[2]); r[3] = f2bf(v[3]);
        ((s16x4*)out)[i] = r;
    }
}

// ---------------- RoPE table: tab[s*32+d] = (cos, sin)(s * 10000^(-d/32)) ----
__global__ void rope_tab_k(float2* __restrict__ tab) {
    int i = blockIdx.x * 256 + threadIdx.x;
    if (i >= SEQ * 32) return;
    int s = i >> 5, d = i & 31;
    float invf = (float)pow(10000.0, -(double)d / 32.0);
    float af = (float)s * invf;               // replicate f32 freqs product
    double a = (double)af;
    tab[i] = make_float2((float)cos(a), (float)sin(a));
}

// ---------------- 128x128 bf16 MFMA GEMM, B given as [N,K] (B^T layout) ------
// MODE 0: qkv + RoPE epilogue, scatter to q[b,h,s,d], k[b,h,s,d], v^T[b,h,d,s]
// MODE 1: plain C[m,n] **f32** write (final output is float32!)
template<int MODE>
__global__ __launch_bounds__(256, 2)
void gemm_bt(const short* __restrict__ A, const short* __restrict__ B,
             short* __restrict__ q, short* __restrict__ kbuf, short* __restrict__ vt,
             float* __restrict__ C, const float2* __restrict__ tab,
             int K, int N) {
    __shared__ __align__(16) short As[128 * 32];
    __shared__ __align__(16) short Bs[128 * 32];
    const int tid  = threadIdx.x;
    const int w    = tid >> 6, lane = tid & 63;
    const int quad = lane >> 4, l16 = lane & 15;
    const int wm = (w >> 1) * 64, wn = (w & 1) * 64;
    const int rowA0 = blockIdx.y * 128;
    const int colB0 = blockIdx.x * 128;

    f32x4 acc[4][4] = {};

    for (int kb = 0; kb < K; kb += 32) {
        __syncthreads();                      // prior-iter LDS readers done
        #pragma unroll
        for (int i = 0; i < 2; ++i) {         // 512 16B chunks, 2 per thread
            int c = i * 256 + w * 64 + lane;  // row = c>>2 (32 bf16/row), col8 = c&3
            async16(&A[(rowA0 + (c >> 2)) * K + kb + (c & 3) * 8],
                    &As[(i * 256 + w * 64) * 8]);
            async16(&B[(colB0 + (c >> 2)) * K + kb + (c & 3) * 8],
                    &Bs[(i * 256 + w * 64) * 8]);
        }
        __syncthreads();                      // vmcnt(0) drain -> data visible

        s16x8 af[4], bfr[4];
        #pragma unroll
        for (int mi = 0; mi < 4; ++mi)
            af[mi] = *(const s16x8*)&As[(wm + mi * 16 + l16) * 32 + quad * 8];
        #pragma unroll
        for (int ni = 0; ni < 4; ++ni)
            bfr[ni] = *(const s16x8*)&Bs[(wn + ni * 16 + l16) * 32 + quad * 8];
        #pragma unroll
        for (int mi = 0; mi < 4; ++mi)
            #pragma unroll
            for (int ni = 0; ni < 4; ++ni)
                acc[mi][ni] = __builtin_amdgcn_mfma_f32_16x16x32_bf16(
                    af[mi], bfr[ni], acc[mi][ni], 0, 0, 0);
    }

    const int cb = colB0 + wn;                // wave's 64-col (one head) window
    if (MODE == 1) {
        #pragma unroll
        for (int mi = 0; mi < 4; ++mi) {
            #pragma unroll
            for (int r = 0; r < 4; ++r) {
                int gm = rowA0 + wm + mi * 16 + quad * 4 + r;
                float* cp = C + (long)gm * N + cb + l16;
                #pragma unroll
                for (int ni = 0; ni < 4; ++ni)
                    cp[ni * 16] = acc[mi][ni][r];   // f32 out
            }
        }
        return;
    }
    // MODE 0: qkv epilogue
    const int sector = cb >> 10;              // 0=q 1=k 2=v
    const int head   = (cb & 1023) >> 6;
    #pragma unroll
    for (int mi = 0; mi < 4; ++mi) {
        #pragma unroll
        for (int r = 0; r < 4; ++r) {
            int gm = rowA0 + wm + mi * 16 + quad * 4 + r;
            int b = gm >> 11, s = gm & 2047;
            float v0 = acc[mi][0][r], v1 = acc[mi][1][r];
            float v2 = acc[mi][2][r], v3 = acc[mi][3][r];
            if (sector < 2) {
                // RoPE on d<32: d0=l16 in [0,16), d1=l16+16 in [16,32)
                // rot(d0) = -x[d0+16] = -v1 ; rot(d1) = x[d1-16] = v0
                float2 cs0 = tab[s * 32 + l16];
                float2 cs1 = tab[s * 32 + 16 + l16];
                float n0 = v0 * cs0.x - v1 * cs0.y;
                float n1 = v1 * cs1.x + v0 * cs1.y;
                short* dst = (sector == 0 ? q : kbuf)
                           + ((long)((b * NHD + head) * SEQ + s)) * HD + l16;
                dst[0]  = f2bf(n0);  dst[16] = f2bf(n1);
                dst[32] = f2bf(v2);  dst[48] = f2bf(v3);
            } else {
                // v stored transposed: vt[((b,h)*64 + d)*SEQ + s]
                short* dst = vt + ((long)((b * NHD + head) * HD) + l16) * SEQ + s;
                dst[0]            = f2bf(v0);
                dst[16 * SEQ]     = f2bf(v1);
                dst[32 * SEQ]     = f2bf(v2);
                dst[48 * SEQ]     = f2bf(v3);
            }
        }
    }
}

// ---------------- flash attention: 64 Q-rows/block, 64-key tiles -------------
__global__ __launch_bounds__(256, 2)
void flash_attn(const short* __restrict__ Q, const short* __restrict__ K,
                const short* __restrict__ Vt, short* __restrict__ O) {
    __shared__ __align__(16) short Qs[64 * 64];
    __shared__ __align__(16) short Ks[64 * 64];
    __shared__ __align__(16) short Vs[64 * 64];   // already transposed: [d][key]
    __shared__ __align__(16) short Ps[4 * 16 * 64];
    const int tid  = threadIdx.x;
    const int w    = tid >> 6, lane = tid & 63;
    const int quad = lane >> 4, l16 = lane & 15;
    const int bh = blockIdx.y;
    const int qb = blockIdx.x * 64;
    const short* Qp = Q  + (long)bh * SEQ * HD + (long)qb * HD;
    const short* Kp = K  + (long)bh * SEQ * HD;
    const short* Vp = Vt + (long)bh * HD * SEQ;

    #pragma unroll
    for (int i = 0; i < 2; ++i) {               // stage Q tile (64x64)
        int c = i * 256 + w * 64 + lane;        // row = c>>3, col8 = c&7
        async16(&Qp[(c >> 3) * HD + (c & 7) * 8], &Qs[(i * 256 + w * 64) * 8]);
    }
    __syncthreads();
    s16x8 aq0 = *(const s16x8*)&Qs[(w * 16 + l16) * 64 + quad * 8];
    s16x8 aq1 = *(const s16x8*)&Qs[(w * 16 + l16) * 64 + 32 + quad * 8];

    float m_i[4], l_i[4];
    f32x4 oacc[4] = {};
    #pragma unroll
    for (int r = 0; r < 4; ++r) { m_i[r] = -1e30f; l_i[r] = 0.f; }

    for (int kt = 0; kt < SEQ / 64; ++kt) {
        __syncthreads();                        // prev-iter Ks/Vs readers done
        #pragma unroll
        for (int i = 0; i < 2; ++i) {
            int c = i * 256 + w * 64 + lane;
            async16(&Kp[(kt * 64 + (c >> 3)) * HD + (c & 7) * 8],
                    &Ks[(i * 256 + w * 64) * 8]);
            async16(&Vp[(c >> 3) * SEQ + kt * 64 + (c & 7) * 8],
                    &Vs[(i * 256 + w * 64) * 8]);
        }
        __syncthreads();

        // S = Q K^T  (wave: 16 rows x 64 keys)
        f32x4 sacc[4] = {};
        #pragma unroll
        for (int ni = 0; ni < 4; ++ni) {
            s16x8 bk0 = *(const s16x8*)&Ks[(ni * 16 + l16) * 64 + quad * 8];
            sacc[ni] = __builtin_amdgcn_mfma_f32_16x16x32_bf16(aq0, bk0, sacc[ni], 0, 0, 0);
            s16x8 bk1 = *(const s16x8*)&Ks[(ni * 16 + l16) * 64 + 32 + quad * 8];
            sacc[ni] = __builtin_amdgcn_mfma_f32_16x16x32_bf16(aq1, bk1, sacc[ni], 0, 0, 0);
        }
        #pragma unroll
        for (int ni = 0; ni < 4; ++ni) sacc[ni] *= 0.125f;   // 1/sqrt(64)

        // online softmax; row m = quad*4+r lives on the quad's 16 lanes
        float alpha[4];
        #pragma unroll
        for (int r = 0; r < 4; ++r) {
            float m0 = fmaxf(fmaxf(sacc[0][r], sacc[1][r]),
                             fmaxf(sacc[2][r], sacc[3][r]));
            m0 = fmaxf(m0, __shfl_xor(m0, 1));
            m0 = fmaxf(m0, __shfl_xor(m0, 2));
            m0 = fmaxf(m0, __shfl_xor(m0, 4));
            m0 = fmaxf(m0, __shfl_xor(m0, 8));
            float mn = fmaxf(m_i[r], m0);
            alpha[r] = __expf(m_i[r] - mn);
            m_i[r] = mn;
        }
        #pragma unroll
        for (int ni = 0; ni < 4; ++ni) {
            #pragma unroll
            for (int r = 0; r < 4; ++r) {
                float p = __expf(sacc[ni][r] - m_i[r]);
                sacc[ni][r] = p;
                // C-layout -> LDS -> A-layout round trip (wave-private rows)
                Ps[(w * 16 + quad * 4 + r) * 64 + ni * 16 + l16] = f2bf(p);
            }
        }
        #pragma unroll
        for (int r = 0; r < 4; ++r) {
            float rs = sacc[0][r] + sacc[1][r] + sacc[2][r] + sacc[3][r];
            rs += __shfl_xor(rs, 1);
            rs += __shfl_xor(rs, 2);
            rs += __shfl_xor(rs, 4);
            rs += __shfl_xor(rs, 8);
            l_i[r] = l_i[r] * alpha[r] + rs;
        }
        #pragma unroll
        for (int nd = 0; nd < 4; ++nd)
            #pragma unroll
            for (int r = 0; r < 4; ++r)
                oacc[nd][r] *= alpha[r];

        // O += P V   (P: 16x64 A-operand, V^T: B-operand from Vs[d][key])
        #pragma unroll
        for (int ks = 0; ks < 2; ++ks) {
            s16x8 ap = *(const s16x8*)&Ps[(w * 16 + l16) * 64 + ks * 32 + quad * 8];
            #pragma unroll
            for (int nd = 0; nd < 4; ++nd) {
                s16x8 bv = *(const s16x8*)&Vs[(nd * 16 + l16) * 64 + ks * 32 + quad * 8];
                oacc[nd] = __builtin_amdgcn_mfma_f32_16x16x32_bf16(ap, bv, oacc[nd], 0, 0, 0);
            }
        }
    }

    const int b = bh >> 4, h = bh & 15;
    #pragma unroll
    for (int r = 0; r < 4; ++r) {
        int srow = qb + w * 16 + quad * 4 + r;
        float inv = 1.0f / l_i[r];
        short* op = O + ((long)(b * SEQ + srow) * HDIM) + h * HD + l16;
        #pragma unroll
        for (int nd = 0; nd < 4; ++nd)
            op[nd * 16] = f2bf(oacc[nd][r] * inv);
    }
}

extern "C" void kernel_launch(void* const* d_in, const int* in_sizes, int n_in,
                              void* d_out, int out_size, void* d_ws, size_t ws_size,
                              hipStream_t stream) {
    // Inputs are f32 (R1's NaN proved it); assign by element count as insurance.
    const void* x_raw  = d_in[0];
    const void* Wq_raw = d_in[1];
    const void* Wp_raw = d_in[2];
    for (int i = 0; i < n_in; ++i) {
        if      (in_sizes[i] == 4096 * 1024) x_raw  = d_in[i];  // [2,2048,1024]
        else if (in_sizes[i] == 3072 * 1024) Wq_raw = d_in[i];  // [3072,1024]
        else if (in_sizes[i] == 1024 * 1024) Wp_raw = d_in[i];  // [1024,1024]
    }
    float* out = (float*)d_out;               // [2,2048,1024] FLOAT32 output

    const size_t MB = 1u << 20;
    char* ws = (char*)d_ws;
    short*  q    = (short*)(ws);              // [2,16,2048,64]  8 MB
    short*  k    = (short*)(ws +  8 * MB);    // [2,16,2048,64]  8 MB
    short*  vt   = (short*)(ws + 16 * MB);    // [2,16,64,2048]  8 MB (V^T)
    short*  xbf  = (short*)(ws + 24 * MB);    // [4096,1024]     8 MB (att reuses)
    short*  att  = xbf;                       // xbf consumed by gemm0 first
    short*  wqkv = (short*)(ws + 32 * MB);    // [3072,1024]     6 MB
    short*  wprj = (short*)(ws + 38 * MB);    // [1024,1024]     2 MB
    float2* tab  = (float2*)(ws + 40 * MB);   // [2048,32]       512 KB
    int*    flag = (int*)(ws + 40 * MB + 512 * 1024);

    detect_k<<<dim3(1), dim3(256), 0, stream>>>((const unsigned short*)x_raw, flag);

    cvt_k<<<dim3(4096 * 1024 / 4 / 256), dim3(256), 0, stream>>>(
        x_raw, xbf, flag, 4096 * 1024 / 4);
    cvt_k<<<dim3(3072 * 1024 / 4 / 256), dim3(256), 0, stream>>>(
        Wq_raw, wqkv, flag, 3072 * 1024 / 4);
    cvt_k<<<dim3(1024 * 1024 / 4 / 256), dim3(256), 0, stream>>>(
        Wp_raw, wprj, flag, 1024 * 1024 / 4);

    rope_tab_k<<<dim3(SEQ * 32 / 256), dim3(256), 0, stream>>>(tab);

    gemm_bt<0><<<dim3(3072 / 128, 4096 / 128), dim3(256), 0, stream>>>(
        xbf, wqkv, q, k, vt, (float*)nullptr, tab, 1024, 3072);

    flash_attn<<<dim3(SEQ / 64, 2 * NHD), dim3(256), 0, stream>>>(q, k, vt, att);

    gemm_bt<1><<<dim3(1024 / 128, 4096 / 128), dim3(256), 0, stream>>>(
        att, wprj, (short*)nullptr, (short*)nullptr, (short*)nullptr, out, tab, 1024, 1024);
}

// Round 7
// 251.224 us; speedup vs baseline: 1.1720x; 1.1720x over previous
//
#include <hip/hip_runtime.h>
#include <math.h>

#define SEQ  2048
#define NHD  16
#define HD   64
#define HDIM 1024

typedef short s16x8 __attribute__((ext_vector_type(8)));   // 8 x bf16 (4 VGPRs)
typedef short s16x4 __attribute__((ext_vector_type(4)));
typedef float f32x4 __attribute__((ext_vector_type(4)));

typedef const __attribute__((address_space(1))) unsigned int* gp_t;
typedef __attribute__((address_space(3))) unsigned int* lp_t;

__device__ __forceinline__ void async16(const short* g, short* l) {
    // 16B per lane, LDS dest = wave-uniform base + lane*16 (no per-lane scatter)
    __builtin_amdgcn_global_load_lds((gp_t)g, (lp_t)l, 16, 0, 0);
}

__device__ __forceinline__ short f2bf(float f) {   // RNE f32 -> bf16 bits
    unsigned int u = __float_as_uint(f);
    u += 0x7fff + ((u >> 16) & 1);
    return (short)(u >> 16);
}

// ---------------- input dtype detector (insurance) ---------------------------
__global__ void detect_k(const unsigned short* __restrict__ x, int* __restrict__ flag) {
    int cnt = 0;
    #pragma unroll 4
    for (int j = 0; j < 32; ++j) {
        unsigned short h = x[threadIdx.x * 32 + j];
        int e = (h >> 7) & 0xFF;
        cnt += (e >= 100 && e <= 140) ? 1 : 0;
    }
    __shared__ int tot;
    if (threadIdx.x == 0) tot = 0;
    __syncthreads();
    atomicAdd(&tot, cnt);
    __syncthreads();
    if (threadIdx.x == 0) *flag = (tot > (8192 * 9) / 10) ? 1 : 0;
}

// ---------------- convert input -> canonical bf16 ----------------------------
__global__ void cvt_k(const void* __restrict__ in, short* __restrict__ out,
                      const int* __restrict__ flag, int n4) {
    int i = blockIdx.x * 256 + threadIdx.x;
    if (i >= n4) return;
    if (*flag) {
        ((s16x4*)out)[i] = ((const s16x4*)in)[i];
    } else {
        f32x4 v = ((const f32x4*)in)[i];
        s16x4 r;
        r[0] = f2bf(v[0]); r[1] = f2bf(v[1]);
        r[2] = f2bf(v[2]); r[3] = f2bf(v[3]);
        ((s16x4*)out)[i] = r;
    }
}

// ---------------- RoPE table: tab[s*32+d] = (cos, sin)(s * 10000^(-d/32)) ----
__global__ void rope_tab_k(float2* __restrict__ tab) {
    int i = blockIdx.x * 256 + threadIdx.x;
    if (i >= SEQ * 32) return;
    int s = i >> 5, d = i & 31;
    float invf = (float)pow(10000.0, -(double)d / 32.0);
    float af = (float)s * invf;               // replicate f32 freqs product
    double a = (double)af;
    tab[i] = make_float2((float)cos(a), (float)sin(a));
}

// ---------------- 128x128 bf16 MFMA GEMM, B given as [N,K] (B^T layout) ------
// LDS rows = 32 shorts = 4 x 16B chunks; chunk (r,c) stored at slot c^(r&3)
// -> fragment b128 reads are 2-way (free) instead of 8-way conflicted.
// MODE 0: qkv + RoPE epilogue -> q[b,h,s,d], k[b,h,s,d], v^T[b,h,d,s]
// MODE 1: plain C[m,n] f32 write (final output dtype)
template<int MODE>
__global__ __launch_bounds__(256, 2)
void gemm_bt(const short* __restrict__ A, const short* __restrict__ B,
             short* __restrict__ q, short* __restrict__ kbuf, short* __restrict__ vt,
             float* __restrict__ C, const float2* __restrict__ tab,
             int K, int N) {
    __shared__ __align__(16) short As[128 * 32];
    __shared__ __align__(16) short Bs[128 * 32];
    const int tid  = threadIdx.x;
    const int w    = tid >> 6, lane = tid & 63;
    const int quad = lane >> 4, l16 = lane & 15;
    const int wm = (w >> 1) * 64, wn = (w & 1) * 64;
    const int rowA0 = blockIdx.y * 128;
    const int colB0 = blockIdx.x * 128;

    f32x4 acc[4][4] = {};

    for (int kb = 0; kb < K; kb += 32) {
        __syncthreads();                      // prior-iter LDS readers done
        #pragma unroll
        for (int i = 0; i < 2; ++i) {         // 512 16B chunks, 2 per thread
            int cidx = i * 256 + w * 64 + lane;
            int row = cidx >> 2, sc = cidx & 3;
            int c = sc ^ (row & 3);           // XOR swizzle: fetch chunk c into slot sc
            async16(&A[(long)(rowA0 + row) * K + kb + c * 8],
                    &As[(i * 256 + w * 64) * 8]);
            async16(&B[(long)(colB0 + row) * K + kb + c * 8],
                    &Bs[(i * 256 + w * 64) * 8]);
        }
        __syncthreads();                      // vmcnt(0) drain -> data visible

        s16x8 af[4], bfr[4];
        #pragma unroll
        for (int mi = 0; mi < 4; ++mi) {
            int slot = quad ^ (l16 & 3);
            af[mi] = *(const s16x8*)&As[(wm + mi * 16 + l16) * 32 + slot * 8];
        }
        #pragma unroll
        for (int ni = 0; ni < 4; ++ni) {
            int slot = quad ^ (l16 & 3);
            bfr[ni] = *(const s16x8*)&Bs[(wn + ni * 16 + l16) * 32 + slot * 8];
        }
        #pragma unroll
        for (int mi = 0; mi < 4; ++mi)
            #pragma unroll
            for (int ni = 0; ni < 4; ++ni)
                acc[mi][ni] = __builtin_amdgcn_mfma_f32_16x16x32_bf16(
                    af[mi], bfr[ni], acc[mi][ni], 0, 0, 0);
    }

    const int cb = colB0 + wn;                // wave's 64-col (one head) window
    if (MODE == 1) {
        #pragma unroll
        for (int mi = 0; mi < 4; ++mi) {
            #pragma unroll
            for (int r = 0; r < 4; ++r) {
                int gm = rowA0 + wm + mi * 16 + quad * 4 + r;
                float* cp = C + (long)gm * N + cb + l16;
                #pragma unroll
                for (int ni = 0; ni < 4; ++ni)
                    cp[ni * 16] = acc[mi][ni][r];
            }
        }
        return;
    }
    // MODE 0: qkv epilogue
    const int sector = cb >> 10;              // 0=q 1=k 2=v
    const int head   = (cb & 1023) >> 6;
    if (sector < 2) {
        #pragma unroll
        for (int mi = 0; mi < 4; ++mi) {
            #pragma unroll
            for (int r = 0; r < 4; ++r) {
                int gm = rowA0 + wm + mi * 16 + quad * 4 + r;
                int b = gm >> 11, s = gm & 2047;
                float v0 = acc[mi][0][r], v1 = acc[mi][1][r];
                float v2 = acc[mi][2][r], v3 = acc[mi][3][r];
                // RoPE on d<32: d0=l16, d1=l16+16; rot(d0)=-x[d0+16], rot(d1)=x[d1-16]
                float2 cs0 = tab[s * 32 + l16];
                float2 cs1 = tab[s * 32 + 16 + l16];
                float n0 = v0 * cs0.x - v1 * cs0.y;
                float n1 = v1 * cs1.x + v0 * cs1.y;
                short* dst = (sector == 0 ? q : kbuf)
                           + ((long)((b * NHD + head) * SEQ + s)) * HD + l16;
                dst[0]  = f2bf(n0);  dst[16] = f2bf(n1);
                dst[32] = f2bf(v2);  dst[48] = f2bf(v3);
            }
        }
    } else {
        // v stored transposed: vt[((b,h)*64+d)*SEQ + s]; pack r=0..3 (consec s)
        #pragma unroll
        for (int mi = 0; mi < 4; ++mi) {
            int srow = rowA0 + wm + mi * 16 + quad * 4;
            int b = srow >> 11, s0 = srow & 2047;
            #pragma unroll
            for (int ni = 0; ni < 4; ++ni) {
                s16x4 pk;
                #pragma unroll
                for (int r = 0; r < 4; ++r) pk[r] = f2bf(acc[mi][ni][r]);
                *(s16x4*)&vt[((long)((b * NHD + head) * HD + ni * 16 + l16)) * SEQ + s0] = pk;
            }
        }
    }
}

// ---------------- flash attention: 64 Q-rows/block, 64-key tiles -------------
// All LDS tiles 64 rows x 64 shorts = 8 x 16B chunks/row, XOR-swizzled:
// chunk (r,c) lives at slot c^(r&7) -> b128 fragment reads conflict-free.
__global__ __launch_bounds__(256, 2)
void flash_attn(const short* __restrict__ Q, const short* __restrict__ K,
                const short* __restrict__ Vt, short* __restrict__ O) {
    __shared__ __align__(16) short Qs[64 * 64];
    __shared__ __align__(16) short Ks[64 * 64];
    __shared__ __align__(16) short Vs[64 * 64];   // V^T: rows = d, cols = key
    __shared__ __align__(16) short Ps[4 * 16 * 64];
    const int tid  = threadIdx.x;
    const int w    = tid >> 6, lane = tid & 63;
    const int quad = lane >> 4, l16 = lane & 15;
    const int bh = blockIdx.y;
    const int qb = blockIdx.x * 64;
    const short* Qp = Q  + (long)bh * SEQ * HD + (long)qb * HD;
    const short* Kp = K  + (long)bh * SEQ * HD;
    const short* Vp = Vt + (long)bh * HD * SEQ;

    #pragma unroll
    for (int i = 0; i < 2; ++i) {               // stage Q tile (64x64), swizzled
        int cidx = i * 256 + w * 64 + lane;
        int row = cidx >> 3, sc = cidx & 7;
        int c = sc ^ (row & 7);
        async16(&Qp[row * HD + c * 8], &Qs[(i * 256 + w * 64) * 8]);
    }
    __syncthreads();
    s16x8 aq0 = *(const s16x8*)&Qs[(w * 16 + l16) * 64 + (quad ^ (l16 & 7)) * 8];
    s16x8 aq1 = *(const s16x8*)&Qs[(w * 16 + l16) * 64 + ((4 + quad) ^ (l16 & 7)) * 8];

    float m_i[4], l_i[4];
    f32x4 oacc[4] = {};
    #pragma unroll
    for (int r = 0; r < 4; ++r) { m_i[r] = -1e30f; l_i[r] = 0.f; }

    for (int kt = 0; kt < SEQ / 64; ++kt) {
        __syncthreads();                        // prev-iter Ks/Vs readers done
        #pragma unroll
        for (int i = 0; i < 2; ++i) {
            int cidx = i * 256 + w * 64 + lane;
            int row = cidx >> 3, sc = cidx & 7;
            int c = sc ^ (row & 7);
            async16(&Kp[(kt * 64 + row) * HD + c * 8], &Ks[(i * 256 + w * 64) * 8]);
            async16(&Vp[(long)row * SEQ + kt * 64 + c * 8], &Vs[(i * 256 + w * 64) * 8]);
        }
        __syncthreads();

        // S = Q K^T  (wave: 16 rows x 64 keys)
        f32x4 sacc[4] = {};
        #pragma unroll
        for (int ni = 0; ni < 4; ++ni) {
            s16x8 bk0 = *(const s16x8*)&Ks[(ni * 16 + l16) * 64 + (quad ^ (l16 & 7)) * 8];
            sacc[ni] = __builtin_amdgcn_mfma_f32_16x16x32_bf16(aq0, bk0, sacc[ni], 0, 0, 0);
            s16x8 bk1 = *(const s16x8*)&Ks[(ni * 16 + l16) * 64 + ((4 + quad) ^ (l16 & 7)) * 8];
            sacc[ni] = __builtin_amdgcn_mfma_f32_16x16x32_bf16(aq1, bk1, sacc[ni], 0, 0, 0);
        }
        #pragma unroll
        for (int ni = 0; ni < 4; ++ni) sacc[ni] *= 0.125f;   // 1/sqrt(64)

        // online softmax; row m = quad*4+r lives on the quad's 16 lanes
        float alpha[4];
        #pragma unroll
        for (int r = 0; r < 4; ++r) {
            float m0 = fmaxf(fmaxf(sacc[0][r], sacc[1][r]),
                             fmaxf(sacc[2][r], sacc[3][r]));
            m0 = fmaxf(m0, __shfl_xor(m0, 1));
            m0 = fmaxf(m0, __shfl_xor(m0, 2));
            m0 = fmaxf(m0, __shfl_xor(m0, 4));
            m0 = fmaxf(m0, __shfl_xor(m0, 8));
            float mn = fmaxf(m_i[r], m0);
            alpha[r] = __expf(m_i[r] - mn);
            m_i[r] = mn;
        }
        #pragma unroll
        for (int ni = 0; ni < 4; ++ni) {
            #pragma unroll
            for (int r = 0; r < 4; ++r) {
                float p = __expf(sacc[ni][r] - m_i[r]);
                sacc[ni][r] = p;
                // C-layout -> LDS (swizzled) -> A-layout; wave-private rows
                int row_p = w * 16 + quad * 4 + r;
                int cch = ni * 2 + (l16 >> 3);
                int slot = cch ^ (row_p & 7);
                Ps[row_p * 64 + slot * 8 + (l16 & 7)] = f2bf(p);
            }
        }
        #pragma unroll
        for (int r = 0; r < 4; ++r) {
            float rs = sacc[0][r] + sacc[1][r] + sacc[2][r] + sacc[3][r];
            rs += __shfl_xor(rs, 1);
            rs += __shfl_xor(rs, 2);
            rs += __shfl_xor(rs, 4);
            rs += __shfl_xor(rs, 8);
            l_i[r] = l_i[r] * alpha[r] + rs;
        }
        #pragma unroll
        for (int nd = 0; nd < 4; ++nd)
            #pragma unroll
            for (int r = 0; r < 4; ++r)
                oacc[nd][r] *= alpha[r];

        // O += P V   (P: 16x64 A-operand; V^T: B-operand from Vs[d][key])
        #pragma unroll
        for (int ks = 0; ks < 2; ++ks) {
            s16x8 ap = *(const s16x8*)&Ps[(w * 16 + l16) * 64
                                          + ((ks * 4 + quad) ^ (l16 & 7)) * 8];
            #pragma unroll
            for (int nd = 0; nd < 4; ++nd) {
                s16x8 bv = *(const s16x8*)&Vs[(nd * 16 + l16) * 64
                                              + ((ks * 4 + quad) ^ (l16 & 7)) * 8];
                oacc[nd] = __builtin_amdgcn_mfma_f32_16x16x32_bf16(ap, bv, oacc[nd], 0, 0, 0);
            }
        }
    }

    const int b = bh >> 4, h = bh & 15;
    #pragma unroll
    for (int r = 0; r < 4; ++r) {
        int srow = qb + w * 16 + quad * 4 + r;
        float inv = 1.0f / l_i[r];
        short* op = O + ((long)(b * SEQ + srow) * HDIM) + h * HD + l16;
        #pragma unroll
        for (int nd = 0; nd < 4; ++nd)
            op[nd * 16] = f2bf(oacc[nd][r] * inv);
    }
}

extern "C" void kernel_launch(void* const* d_in, const int* in_sizes, int n_in,
                              void* d_out, int out_size, void* d_ws, size_t ws_size,
                              hipStream_t stream) {
    const void* x_raw  = d_in[0];
    const void* Wq_raw = d_in[1];
    const void* Wp_raw = d_in[2];
    for (int i = 0; i < n_in; ++i) {
        if      (in_sizes[i] == 4096 * 1024) x_raw  = d_in[i];  // [2,2048,1024]
        else if (in_sizes[i] == 3072 * 1024) Wq_raw = d_in[i];  // [3072,1024]
        else if (in_sizes[i] == 1024 * 1024) Wp_raw = d_in[i];  // [1024,1024]
    }
    float* out = (float*)d_out;               // [2,2048,1024] f32 output

    const size_t MB = 1u << 20;
    char* ws = (char*)d_ws;
    short*  q    = (short*)(ws);              // [2,16,2048,64]  8 MB
    short*  k    = (short*)(ws +  8 * MB);    // [2,16,2048,64]  8 MB
    short*  vt   = (short*)(ws + 16 * MB);    // [2,16,64,2048]  8 MB (V^T)
    short*  xbf  = (short*)(ws + 24 * MB);    // [4096,1024]     8 MB (att reuses)
    short*  att  = xbf;                       // xbf consumed by gemm0 first
    short*  wqkv = (short*)(ws + 32 * MB);    // [3072,1024]     6 MB
    short*  wprj = (short*)(ws + 38 * MB);    // [1024,1024]     2 MB
    float2* tab  = (float2*)(ws + 40 * MB);   // [2048,32]       512 KB
    int*    flag = (int*)(ws + 40 * MB + 512 * 1024);

    detect_k<<<dim3(1), dim3(256), 0, stream>>>((const unsigned short*)x_raw, flag);

    cvt_k<<<dim3(4096 * 1024 / 4 / 256), dim3(256), 0, stream>>>(
        x_raw, xbf, flag, 4096 * 1024 / 4);
    cvt_k<<<dim3(3072 * 1024 / 4 / 256), dim3(256), 0, stream>>>(
        Wq_raw, wqkv, flag, 3072 * 1024 / 4);
    cvt_k<<<dim3(1024 * 1024 / 4 / 256), dim3(256), 0, stream>>>(
        Wp_raw, wprj, flag, 1024 * 1024 / 4);

    rope_tab_k<<<dim3(SEQ * 32 / 256), dim3(256), 0, stream>>>(tab);

    gemm_bt<0><<<dim3(3072 / 128, 4096 / 128), dim3(256), 0, stream>>>(
        xbf, wqkv, q, k, vt, (float*)nullptr, tab, 1024, 3072);

    flash_attn<<<dim3(SEQ / 64, 2 * NHD), dim3(256), 0, stream>>>(q, k, vt, att);

    gemm_bt<1><<<dim3(1024 / 128, 4096 / 128), dim3(256), 0, stream>>>(
        att, wprj, (short*)nullptr, (short*)nullptr, (short*)nullptr, out, tab, 1024, 1024);
}

// Round 8
// 239.437 us; speedup vs baseline: 1.2297x; 1.0492x over previous
//
#include <hip/hip_runtime.h>
#include <math.h>

#define SEQ  2048
#define NHD  16
#define HD   64
#define HDIM 1024

typedef short s16x8 __attribute__((ext_vector_type(8)));   // 8 x bf16 (4 VGPRs)
typedef short s16x4 __attribute__((ext_vector_type(4)));
typedef float f32x4 __attribute__((ext_vector_type(4)));

typedef const __attribute__((address_space(1))) unsigned int* gp_t;
typedef __attribute__((address_space(3))) unsigned int* lp_t;

__device__ __forceinline__ void async16(const short* g, short* l) {
    // 16B per lane, LDS dest = wave-uniform base + lane*16 (no per-lane scatter)
    __builtin_amdgcn_global_load_lds((gp_t)g, (lp_t)l, 16, 0, 0);
}

__device__ __forceinline__ short f2bf(float f) {   // RNE f32 -> bf16 bits
    unsigned int u = __float_as_uint(f);
    u += 0x7fff + ((u >> 16) & 1);
    return (short)(u >> 16);
}

// ---------------- input dtype detector (insurance) ---------------------------
__global__ void detect_k(const unsigned short* __restrict__ x, int* __restrict__ flag) {
    int cnt = 0;
    #pragma unroll 4
    for (int j = 0; j < 32; ++j) {
        unsigned short h = x[threadIdx.x * 32 + j];
        int e = (h >> 7) & 0xFF;
        cnt += (e >= 100 && e <= 140) ? 1 : 0;
    }
    __shared__ int tot;
    if (threadIdx.x == 0) tot = 0;
    __syncthreads();
    atomicAdd(&tot, cnt);
    __syncthreads();
    if (threadIdx.x == 0) *flag = (tot > (8192 * 9) / 10) ? 1 : 0;
}

// ---------------- convert input -> canonical bf16 ----------------------------
__global__ void cvt_k(const void* __restrict__ in, short* __restrict__ out,
                      const int* __restrict__ flag, int n4) {
    int i = blockIdx.x * 256 + threadIdx.x;
    if (i >= n4) return;
    if (*flag) {
        ((s16x4*)out)[i] = ((const s16x4*)in)[i];
    } else {
        f32x4 v = ((const f32x4*)in)[i];
        s16x4 r;
        r[0] = f2bf(v[0]); r[1] = f2bf(v[1]);
        r[2] = f2bf(v[2]); r[3] = f2bf(v[3]);
        ((s16x4*)out)[i] = r;
    }
}

// ---------------- RoPE table: tab[s*32+d] = (cos, sin)(s * 10000^(-d/32)) ----
__global__ void rope_tab_k(float2* __restrict__ tab) {
    int i = blockIdx.x * 256 + threadIdx.x;
    if (i >= SEQ * 32) return;
    int s = i >> 5, d = i & 31;
    float invf = (float)pow(10000.0, -(double)d / 32.0);
    float af = (float)s * invf;               // replicate f32 freqs product
    double a = (double)af;
    tab[i] = make_float2((float)cos(a), (float)sin(a));
}

// ---------------- 128x128 bf16 MFMA GEMM, B given as [N,K] (B^T layout) ------
// LDS rows = 32 shorts = 4 x 16B chunks; chunk (r,c) stored at slot c^(r&3).
// MODE 0: qkv + RoPE epilogue -> q[b,h,s,d] (SCALED by 1/8), k, v^T[b,h,d,s]
// MODE 1: plain C[m,n] f32 write (final output dtype)
template<int MODE>
__global__ __launch_bounds__(256, 2)
void gemm_bt(const short* __restrict__ A, const short* __restrict__ B,
             short* __restrict__ q, short* __restrict__ kbuf, short* __restrict__ vt,
             float* __restrict__ C, const float2* __restrict__ tab,
             int K, int N) {
    __shared__ __align__(16) short As[128 * 32];
    __shared__ __align__(16) short Bs[128 * 32];
    const int tid  = threadIdx.x;
    const int w    = tid >> 6, lane = tid & 63;
    const int quad = lane >> 4, l16 = lane & 15;
    const int wm = (w >> 1) * 64, wn = (w & 1) * 64;
    const int rowA0 = blockIdx.y * 128;
    const int colB0 = blockIdx.x * 128;

    f32x4 acc[4][4] = {};

    for (int kb = 0; kb < K; kb += 32) {
        __syncthreads();
        #pragma unroll
        for (int i = 0; i < 2; ++i) {
            int cidx = i * 256 + w * 64 + lane;
            int row = cidx >> 2, sc = cidx & 3;
            int c = sc ^ (row & 3);           // XOR swizzle
            async16(&A[(long)(rowA0 + row) * K + kb + c * 8],
                    &As[(i * 256 + w * 64) * 8]);
            async16(&B[(long)(colB0 + row) * K + kb + c * 8],
                    &Bs[(i * 256 + w * 64) * 8]);
        }
        __syncthreads();

        s16x8 af[4], bfr[4];
        const int slot = quad ^ (l16 & 3);
        #pragma unroll
        for (int mi = 0; mi < 4; ++mi)
            af[mi] = *(const s16x8*)&As[(wm + mi * 16 + l16) * 32 + slot * 8];
        #pragma unroll
        for (int ni = 0; ni < 4; ++ni)
            bfr[ni] = *(const s16x8*)&Bs[(wn + ni * 16 + l16) * 32 + slot * 8];
        #pragma unroll
        for (int mi = 0; mi < 4; ++mi)
            #pragma unroll
            for (int ni = 0; ni < 4; ++ni)
                acc[mi][ni] = __builtin_amdgcn_mfma_f32_16x16x32_bf16(
                    af[mi], bfr[ni], acc[mi][ni], 0, 0, 0);
    }

    const int cb = colB0 + wn;                // wave's 64-col (one head) window
    if (MODE == 1) {
        #pragma unroll
        for (int mi = 0; mi < 4; ++mi) {
            #pragma unroll
            for (int r = 0; r < 4; ++r) {
                int gm = rowA0 + wm + mi * 16 + quad * 4 + r;
                float* cp = C + (long)gm * N + cb + l16;
                #pragma unroll
                for (int ni = 0; ni < 4; ++ni)
                    cp[ni * 16] = acc[mi][ni][r];
            }
        }
        return;
    }
    // MODE 0: qkv epilogue
    const int sector = cb >> 10;              // 0=q 1=k 2=v
    const int head   = (cb & 1023) >> 6;
    if (sector < 2) {
        const float sc = (sector == 0) ? 0.125f : 1.0f;  // fold 1/sqrt(64) into q
        #pragma unroll
        for (int mi = 0; mi < 4; ++mi) {
            #pragma unroll
            for (int r = 0; r < 4; ++r) {
                int gm = rowA0 + wm + mi * 16 + quad * 4 + r;
                int b = gm >> 11, s = gm & 2047;
                float v0 = acc[mi][0][r], v1 = acc[mi][1][r];
                float v2 = acc[mi][2][r], v3 = acc[mi][3][r];
                // RoPE on d<32: d0=l16, d1=l16+16; rot(d0)=-x[d0+16], rot(d1)=x[d1-16]
                float2 cs0 = tab[s * 32 + l16];
                float2 cs1 = tab[s * 32 + 16 + l16];
                float n0 = v0 * cs0.x - v1 * cs0.y;
                float n1 = v1 * cs1.x + v0 * cs1.y;
                short* dst = (sector == 0 ? q : kbuf)
                           + ((long)((b * NHD + head) * SEQ + s)) * HD + l16;
                dst[0]  = f2bf(n0 * sc);  dst[16] = f2bf(n1 * sc);
                dst[32] = f2bf(v2 * sc);  dst[48] = f2bf(v3 * sc);
            }
        }
    } else {
        // v stored transposed: vt[((b,h)*64+d)*SEQ + s]; pack r=0..3 (consec s)
        #pragma unroll
        for (int mi = 0; mi < 4; ++mi) {
            int srow = rowA0 + wm + mi * 16 + quad * 4;
            int b = srow >> 11, s0 = srow & 2047;
            #pragma unroll
            for (int ni = 0; ni < 4; ++ni) {
                s16x4 pk;
                #pragma unroll
                for (int r = 0; r < 4; ++r) pk[r] = f2bf(acc[mi][ni][r]);
                *(s16x4*)&vt[((long)((b * NHD + head) * HD + ni * 16 + l16)) * SEQ + s0] = pk;
            }
        }
    }
}

// ---------------- flash attention: 128 Q-rows/block, 32 rows/wave ------------
// K/V fragments feed 2 MFMA each (mi=0,1); row-sum l computed by MFMA with a
// constant all-ones B fragment (lane-local l, no shuffle reduction).
// All LDS tiles XOR-swizzled: chunk (r,c) at slot c^(r&7) -> conflict-free.
__global__ __launch_bounds__(256, 2)
void flash_attn(const short* __restrict__ Q, const short* __restrict__ K,
                const short* __restrict__ Vt, short* __restrict__ O) {
    __shared__ __align__(16) short Qs[128 * 64];
    __shared__ __align__(16) short Ks[64 * 64];
    __shared__ __align__(16) short Vs[64 * 64];   // V^T: rows = d, cols = key
    __shared__ __align__(16) short Ps[128 * 64];  // 32 rows per wave
    const int tid  = threadIdx.x;
    const int w    = tid >> 6, lane = tid & 63;
    const int quad = lane >> 4, l16 = lane & 15;
    const int bh = blockIdx.y;
    const int qb = blockIdx.x * 128;
    const short* Qp = Q  + (long)bh * SEQ * HD + (long)qb * HD;
    const short* Kp = K  + (long)bh * SEQ * HD;
    const short* Vp = Vt + (long)bh * HD * SEQ;

    #pragma unroll
    for (int i = 0; i < 4; ++i) {               // stage Q tile (128x64), swizzled
        int cidx = i * 256 + w * 64 + lane;
        int row = cidx >> 3, sc = cidx & 7;
        int c = sc ^ (row & 7);
        async16(&Qp[row * HD + c * 8], &Qs[(i * 256 + w * 64) * 8]);
    }
    __syncthreads();
    s16x8 aq[2][2];
    #pragma unroll
    for (int mi = 0; mi < 2; ++mi)
        #pragma unroll
        for (int ks = 0; ks < 2; ++ks)
            aq[mi][ks] = *(const s16x8*)&Qs[(w * 32 + mi * 16 + l16) * 64
                                            + ((ks * 4 + quad) ^ (l16 & 7)) * 8];

    s16x8 ones;
    #pragma unroll
    for (int j = 0; j < 8; ++j) ones[j] = (short)0x3F80;   // bf16 1.0

    float m_i[2][4];
    f32x4 oacc[2][4] = {};
    f32x4 lacc[2] = {};
    #pragma unroll
    for (int mi = 0; mi < 2; ++mi)
        #pragma unroll
        for (int r = 0; r < 4; ++r) m_i[mi][r] = -1e30f;

    for (int kt = 0; kt < SEQ / 64; ++kt) {
        __syncthreads();                        // prev-iter Ks/Vs readers done
        #pragma unroll
        for (int i = 0; i < 2; ++i) {
            int cidx = i * 256 + w * 64 + lane;
            int row = cidx >> 3, sc = cidx & 7;
            int c = sc ^ (row & 7);
            async16(&Kp[(kt * 64 + row) * HD + c * 8], &Ks[(i * 256 + w * 64) * 8]);
            async16(&Vp[(long)row * SEQ + kt * 64 + c * 8], &Vs[(i * 256 + w * 64) * 8]);
        }
        __syncthreads();

        // S = Q K^T  (wave: 32 rows x 64 keys; q pre-scaled by 1/8)
        f32x4 sacc[2][4] = {};
        #pragma unroll
        for (int ni = 0; ni < 4; ++ni) {
            s16x8 bk0 = *(const s16x8*)&Ks[(ni * 16 + l16) * 64 + (quad ^ (l16 & 7)) * 8];
            s16x8 bk1 = *(const s16x8*)&Ks[(ni * 16 + l16) * 64 + ((4 + quad) ^ (l16 & 7)) * 8];
            #pragma unroll
            for (int mi = 0; mi < 2; ++mi) {
                sacc[mi][ni] = __builtin_amdgcn_mfma_f32_16x16x32_bf16(
                    aq[mi][0], bk0, sacc[mi][ni], 0, 0, 0);
                sacc[mi][ni] = __builtin_amdgcn_mfma_f32_16x16x32_bf16(
                    aq[mi][1], bk1, sacc[mi][ni], 0, 0, 0);
            }
        }

        // online softmax; row = w*32 + mi*16 + quad*4 + r on the quad's 16 lanes
        float alpha[2][4];
        #pragma unroll
        for (int mi = 0; mi < 2; ++mi) {
            #pragma unroll
            for (int r = 0; r < 4; ++r) {
                float m0 = fmaxf(fmaxf(sacc[mi][0][r], sacc[mi][1][r]),
                                 fmaxf(sacc[mi][2][r], sacc[mi][3][r]));
                m0 = fmaxf(m0, __shfl_xor(m0, 1));
                m0 = fmaxf(m0, __shfl_xor(m0, 2));
                m0 = fmaxf(m0, __shfl_xor(m0, 4));
                m0 = fmaxf(m0, __shfl_xor(m0, 8));
                float mn = fmaxf(m_i[mi][r], m0);
                alpha[mi][r] = __expf(m_i[mi][r] - mn);
                m_i[mi][r] = mn;
            }
        }
        #pragma unroll
        for (int mi = 0; mi < 2; ++mi) {
            #pragma unroll
            for (int ni = 0; ni < 4; ++ni) {
                #pragma unroll
                for (int r = 0; r < 4; ++r) {
                    float p = __expf(sacc[mi][ni][r] - m_i[mi][r]);
                    int row_p = w * 32 + mi * 16 + quad * 4 + r;
                    int cch = ni * 2 + (l16 >> 3);
                    int slot = cch ^ (row_p & 7);
                    Ps[row_p * 64 + slot * 8 + (l16 & 7)] = f2bf(p);
                }
            }
            #pragma unroll
            for (int nd = 0; nd < 4; ++nd)
                #pragma unroll
                for (int r = 0; r < 4; ++r)
                    oacc[mi][nd][r] *= alpha[mi][r];
            #pragma unroll
            for (int r = 0; r < 4; ++r)
                lacc[mi][r] *= alpha[mi][r];
        }

        // O += P V ; l += P 1  (P rows wave-private: no barrier needed)
        #pragma unroll
        for (int ks = 0; ks < 2; ++ks) {
            s16x8 ap[2];
            #pragma unroll
            for (int mi = 0; mi < 2; ++mi) {
                ap[mi] = *(const s16x8*)&Ps[(w * 32 + mi * 16 + l16) * 64
                                            + ((ks * 4 + quad) ^ (l16 & 7)) * 8];
                lacc[mi] = __builtin_amdgcn_mfma_f32_16x16x32_bf16(
                    ap[mi], ones, lacc[mi], 0, 0, 0);
            }
            #pragma unroll
            for (int nd = 0; nd < 4; ++nd) {
                s16x8 bv = *(const s16x8*)&Vs[(nd * 16 + l16) * 64
                                              + ((ks * 4 + quad) ^ (l16 & 7)) * 8];
                #pragma unroll
                for (int mi = 0; mi < 2; ++mi)
                    oacc[mi][nd] = __builtin_amdgcn_mfma_f32_16x16x32_bf16(
                        ap[mi], bv, oacc[mi][nd], 0, 0, 0);
            }
        }
    }

    const int b = bh >> 4, h = bh & 15;
    #pragma unroll
    for (int mi = 0; mi < 2; ++mi) {
        #pragma unroll
        for (int r = 0; r < 4; ++r) {
            int srow = qb + w * 32 + mi * 16 + quad * 4 + r;
            float inv = 1.0f / lacc[mi][r];     // lane-local: l from ones-MFMA
            short* op = O + ((long)(b * SEQ + srow) * HDIM) + h * HD + l16;
            #pragma unroll
            for (int nd = 0; nd < 4; ++nd)
                op[nd * 16] = f2bf(oacc[mi][nd][r] * inv);
        }
    }
}

extern "C" void kernel_launch(void* const* d_in, const int* in_sizes, int n_in,
                              void* d_out, int out_size, void* d_ws, size_t ws_size,
                              hipStream_t stream) {
    const void* x_raw  = d_in[0];
    const void* Wq_raw = d_in[1];
    const void* Wp_raw = d_in[2];
    for (int i = 0; i < n_in; ++i) {
        if      (in_sizes[i] == 4096 * 1024) x_raw  = d_in[i];  // [2,2048,1024]
        else if (in_sizes[i] == 3072 * 1024) Wq_raw = d_in[i];  // [3072,1024]
        else if (in_sizes[i] == 1024 * 1024) Wp_raw = d_in[i];  // [1024,1024]
    }
    float* out = (float*)d_out;               // [2,2048,1024] f32 output

    const size_t MB = 1u << 20;
    char* ws = (char*)d_ws;
    short*  q    = (short*)(ws);              // [2,16,2048,64]  8 MB (pre-scaled 1/8)
    short*  k    = (short*)(ws +  8 * MB);    // [2,16,2048,64]  8 MB
    short*  vt   = (short*)(ws + 16 * MB);    // [2,16,64,2048]  8 MB (V^T)
    short*  xbf  = (short*)(ws + 24 * MB);    // [4096,1024]     8 MB (att reuses)
    short*  att  = xbf;                       // xbf consumed by gemm0 first
    short*  wqkv = (short*)(ws + 32 * MB);    // [3072,1024]     6 MB
    short*  wprj = (short*)(ws + 38 * MB);    // [1024,1024]     2 MB
    float2* tab  = (float2*)(ws + 40 * MB);   // [2048,32]       512 KB
    int*    flag = (int*)(ws + 40 * MB + 512 * 1024);

    detect_k<<<dim3(1), dim3(256), 0, stream>>>((const unsigned short*)x_raw, flag);

    cvt_k<<<dim3(4096 * 1024 / 4 / 256), dim3(256), 0, stream>>>(
        x_raw, xbf, flag, 4096 * 1024 / 4);
    cvt_k<<<dim3(3072 * 1024 / 4 / 256), dim3(256), 0, stream>>>(
        Wq_raw, wqkv, flag, 3072 * 1024 / 4);
    cvt_k<<<dim3(1024 * 1024 / 4 / 256), dim3(256), 0, stream>>>(
        Wp_raw, wprj, flag, 1024 * 1024 / 4);

    rope_tab_k<<<dim3(SEQ * 32 / 256), dim3(256), 0, stream>>>(tab);

    gemm_bt<0><<<dim3(3072 / 128, 4096 / 128), dim3(256), 0, stream>>>(
        xbf, wqkv, q, k, vt, (float*)nullptr, tab, 1024, 3072);

    flash_attn<<<dim3(SEQ / 128, 2 * NHD), dim3(256), 0, stream>>>(q, k, vt, att);

    gemm_bt<1><<<dim3(1024 / 128, 4096 / 128), dim3(256), 0, stream>>>(
        att, wprj, (short*)nullptr, (short*)nullptr, (short*)nullptr, out, tab, 1024, 1024);
}

// Round 9
// 221.623 us; speedup vs baseline: 1.3286x; 1.0804x over previous
//
#include <hip/hip_runtime.h>
#include <math.h>

#define SEQ  2048
#define NHD  16
#define HD   64
#define HDIM 1024

typedef short s16x8 __attribute__((ext_vector_type(8)));   // 8 x bf16 (4 VGPRs)
typedef short s16x4 __attribute__((ext_vector_type(4)));
typedef float f32x4 __attribute__((ext_vector_type(4)));

typedef const __attribute__((address_space(1))) unsigned int* gp_t;
typedef __attribute__((address_space(3))) unsigned int* lp_t;

__device__ __forceinline__ void async16(const short* g, short* l) {
    // 16B per lane, LDS dest = wave-uniform base + lane*16 (no per-lane scatter)
    __builtin_amdgcn_global_load_lds((gp_t)g, (lp_t)l, 16, 0, 0);
}

__device__ __forceinline__ short f2bf(float f) {   // RNE f32 -> bf16 bits
    unsigned int u = __float_as_uint(f);
    u += 0x7fff + ((u >> 16) & 1);
    return (short)(u >> 16);
}

// ---------------- input dtype detector (insurance) ---------------------------
__global__ void detect_k(const unsigned short* __restrict__ x, int* __restrict__ flag) {
    int cnt = 0;
    #pragma unroll 4
    for (int j = 0; j < 32; ++j) {
        unsigned short h = x[threadIdx.x * 32 + j];
        int e = (h >> 7) & 0xFF;
        cnt += (e >= 100 && e <= 140) ? 1 : 0;
    }
    __shared__ int tot;
    if (threadIdx.x == 0) tot = 0;
    __syncthreads();
    atomicAdd(&tot, cnt);
    __syncthreads();
    if (threadIdx.x == 0) *flag = (tot > (8192 * 9) / 10) ? 1 : 0;
}

// ---------------- fused convert: all 3 inputs -> canonical bf16 --------------
#define XG4  (4096 * 1024 / 4)
#define WQG4 (3072 * 1024 / 4)
#define WPG4 (1024 * 1024 / 4)
__global__ void cvt_all_k(const void* __restrict__ xr, const void* __restrict__ wqr,
                          const void* __restrict__ wpr, short* __restrict__ xo,
                          short* __restrict__ wqo, short* __restrict__ wpo,
                          const int* __restrict__ flag) {
    int i = blockIdx.x * 256 + threadIdx.x;
    const void* in; short* out; int j;
    if (i < XG4)             { in = xr;  out = xo;  j = i; }
    else if (i < XG4 + WQG4) { in = wqr; out = wqo; j = i - XG4; }
    else                     { in = wpr; out = wpo; j = i - XG4 - WQG4; }
    if (*flag) {
        ((s16x4*)out)[j] = ((const s16x4*)in)[j];
    } else {
        f32x4 v = ((const f32x4*)in)[j];
        s16x4 r;
        r[0] = f2bf(v[0]); r[1] = f2bf(v[1]);
        r[2] = f2bf(v[2]); r[3] = f2bf(v[3]);
        ((s16x4*)out)[j] = r;
    }
}

// ---------------- RoPE table: tab[s*32+d] = (cos, sin)(s * 10000^(-d/32)) ----
__global__ void rope_tab_k(float2* __restrict__ tab) {
    int i = blockIdx.x * 256 + threadIdx.x;
    if (i >= SEQ * 32) return;
    int s = i >> 5, d = i & 31;
    float invf = (float)pow(10000.0, -(double)d / 32.0);
    float af = (float)s * invf;               // replicate f32 freqs product
    double a = (double)af;
    tab[i] = make_float2((float)cos(a), (float)sin(a));
}

// ---------------- 128x128 bf16 MFMA GEMM, B given as [N,K] (B^T layout) ------
// LDS rows = 32 shorts = 4 x 16B chunks; chunk (r,c) stored at slot c^(r&3).
// MODE 0: qkv + RoPE epilogue -> q[b,h,s,d] (SCALED by 1/8), k, v^T[b,h,d,s]
// MODE 1: plain C[m,n] f32 write (final output dtype)
template<int MODE>
__global__ __launch_bounds__(256, 2)
void gemm_bt(const short* __restrict__ A, const short* __restrict__ B,
             short* __restrict__ q, short* __restrict__ kbuf, short* __restrict__ vt,
             float* __restrict__ C, const float2* __restrict__ tab,
             int K, int N) {
    __shared__ __align__(16) short As[128 * 32];
    __shared__ __align__(16) short Bs[128 * 32];
    const int tid  = threadIdx.x;
    const int w    = tid >> 6, lane = tid & 63;
    const int quad = lane >> 4, l16 = lane & 15;
    const int wm = (w >> 1) * 64, wn = (w & 1) * 64;
    const int rowA0 = blockIdx.y * 128;
    const int colB0 = blockIdx.x * 128;

    f32x4 acc[4][4] = {};

    for (int kb = 0; kb < K; kb += 32) {
        __syncthreads();
        #pragma unroll
        for (int i = 0; i < 2; ++i) {
            int cidx = i * 256 + w * 64 + lane;
            int row = cidx >> 2, sc = cidx & 3;
            int c = sc ^ (row & 3);           // XOR swizzle
            async16(&A[(long)(rowA0 + row) * K + kb + c * 8],
                    &As[(i * 256 + w * 64) * 8]);
            async16(&B[(long)(colB0 + row) * K + kb + c * 8],
                    &Bs[(i * 256 + w * 64) * 8]);
        }
        __syncthreads();

        s16x8 af[4], bfr[4];
        const int slot = quad ^ (l16 & 3);
        #pragma unroll
        for (int mi = 0; mi < 4; ++mi)
            af[mi] = *(const s16x8*)&As[(wm + mi * 16 + l16) * 32 + slot * 8];
        #pragma unroll
        for (int ni = 0; ni < 4; ++ni)
            bfr[ni] = *(const s16x8*)&Bs[(wn + ni * 16 + l16) * 32 + slot * 8];
        #pragma unroll
        for (int mi = 0; mi < 4; ++mi)
            #pragma unroll
            for (int ni = 0; ni < 4; ++ni)
                acc[mi][ni] = __builtin_amdgcn_mfma_f32_16x16x32_bf16(
                    af[mi], bfr[ni], acc[mi][ni], 0, 0, 0);
    }

    const int cb = colB0 + wn;                // wave's 64-col (one head) window
    if (MODE == 1) {
        #pragma unroll
        for (int mi = 0; mi < 4; ++mi) {
            #pragma unroll
            for (int r = 0; r < 4; ++r) {
                int gm = rowA0 + wm + mi * 16 + quad * 4 + r;
                float* cp = C + (long)gm * N + cb + l16;
                #pragma unroll
                for (int ni = 0; ni < 4; ++ni)
                    cp[ni * 16] = acc[mi][ni][r];
            }
        }
        return;
    }
    // MODE 0: qkv epilogue
    const int sector = cb >> 10;              // 0=q 1=k 2=v
    const int head   = (cb & 1023) >> 6;
    if (sector < 2) {
        const float sc = (sector == 0) ? 0.125f : 1.0f;  // fold 1/sqrt(64) into q
        #pragma unroll
        for (int mi = 0; mi < 4; ++mi) {
            #pragma unroll
            for (int r = 0; r < 4; ++r) {
                int gm = rowA0 + wm + mi * 16 + quad * 4 + r;
                int b = gm >> 11, s = gm & 2047;
                float v0 = acc[mi][0][r], v1 = acc[mi][1][r];
                float v2 = acc[mi][2][r], v3 = acc[mi][3][r];
                // RoPE on d<32: d0=l16, d1=l16+16; rot(d0)=-x[d0+16], rot(d1)=x[d1-16]
                float2 cs0 = tab[s * 32 + l16];
                float2 cs1 = tab[s * 32 + 16 + l16];
                float n0 = v0 * cs0.x - v1 * cs0.y;
                float n1 = v1 * cs1.x + v0 * cs1.y;
                short* dst = (sector == 0 ? q : kbuf)
                           + ((long)((b * NHD + head) * SEQ + s)) * HD + l16;
                dst[0]  = f2bf(n0 * sc);  dst[16] = f2bf(n1 * sc);
                dst[32] = f2bf(v2 * sc);  dst[48] = f2bf(v3 * sc);
            }
        }
    } else {
        // v stored transposed: vt[((b,h)*64+d)*SEQ + s]; pack r=0..3 (consec s)
        #pragma unroll
        for (int mi = 0; mi < 4; ++mi) {
            int srow = rowA0 + wm + mi * 16 + quad * 4;
            int b = srow >> 11, s0 = srow & 2047;
            #pragma unroll
            for (int ni = 0; ni < 4; ++ni) {
                s16x4 pk;
                #pragma unroll
                for (int r = 0; r < 4; ++r) pk[r] = f2bf(acc[mi][ni][r]);
                *(s16x4*)&vt[((long)((b * NHD + head) * HD + ni * 16 + l16)) * SEQ + s0] = pk;
            }
        }
    }
}

// ---------------- flash attention v3: S^T formulation, in-register P chain ---
// S^T = K·Q^T (A=K, B=Q). C-layout: lane holds qrow=l16, keys=ki*16+quad*4+r.
// PV via ZERO-PADDED 16x16x32: virtual-k quad*8+j <-> key quad*4+j (j<4),
// j>=4 dead (zeros). B=exp'd P packed in-register; A=V^T b64 + zero high half.
// No Ps LDS round-trip; softmax stats lane-local + 2 shuffles.
__global__ __launch_bounds__(256, 2)
void flash_attn(const short* __restrict__ Q, const short* __restrict__ K,
                const short* __restrict__ Vt, short* __restrict__ O) {
    __shared__ __align__(16) short Qs[128 * 64];
    __shared__ __align__(16) short Ks[64 * 64];
    __shared__ __align__(16) short Vs[64 * 64];   // V^T: rows = d, cols = key
    const int tid  = threadIdx.x;
    const int w    = tid >> 6, lane = tid & 63;
    const int quad = lane >> 4, l16 = lane & 15;
    const int bh = blockIdx.y;
    const int qb = blockIdx.x * 128;
    const short* Qp = Q  + (long)bh * SEQ * HD + (long)qb * HD;
    const short* Kp = K  + (long)bh * SEQ * HD;
    const short* Vp = Vt + (long)bh * HD * SEQ;

    #pragma unroll
    for (int i = 0; i < 4; ++i) {               // stage Q tile (128x64), swizzled
        int cidx = i * 256 + w * 64 + lane;
        int row = cidx >> 3, sc = cidx & 7;
        int c = sc ^ (row & 7);
        async16(&Qp[row * HD + c * 8], &Qs[(i * 256 + w * 64) * 8]);
    }
    __syncthreads();
    s16x8 aq[2][2];                             // B-operand: qrow=l16, k=quad*8+j
    #pragma unroll
    for (int mi = 0; mi < 2; ++mi)
        #pragma unroll
        for (int ks = 0; ks < 2; ++ks)
            aq[mi][ks] = *(const s16x8*)&Qs[(w * 32 + mi * 16 + l16) * 64
                                            + ((ks * 4 + quad) ^ (l16 & 7)) * 8];

    s16x8 ones4 = {};                           // A-frag for l: 1.0 at j<4
    #pragma unroll
    for (int j = 0; j < 4; ++j) ones4[j] = (short)0x3F80;

    float m_i[2] = {-1e30f, -1e30f};            // lane-local: qrow = l16
    f32x4 oacc[2][4] = {};
    f32x4 lacc[2] = {};

    for (int kt = 0; kt < SEQ / 64; ++kt) {
        __syncthreads();                        // prev-iter Ks/Vs readers done
        #pragma unroll
        for (int i = 0; i < 2; ++i) {
            int cidx = i * 256 + w * 64 + lane;
            int row = cidx >> 3, sc = cidx & 7;
            int c = sc ^ (row & 7);
            async16(&Kp[(kt * 64 + row) * HD + c * 8], &Ks[(i * 256 + w * 64) * 8]);
            async16(&Vp[(long)row * SEQ + kt * 64 + c * 8], &Vs[(i * 256 + w * 64) * 8]);
        }
        __syncthreads();

        // S^T = K·Q^T : st[mi][ki] = tile [key=ki*16+quad*4+r][qrow=l16]
        f32x4 st[2][4] = {};
        #pragma unroll
        for (int ki = 0; ki < 4; ++ki) {
            s16x8 ak0 = *(const s16x8*)&Ks[(ki * 16 + l16) * 64 + (quad ^ (l16 & 7)) * 8];
            s16x8 ak1 = *(const s16x8*)&Ks[(ki * 16 + l16) * 64 + ((4 + quad) ^ (l16 & 7)) * 8];
            #pragma unroll
            for (int mi = 0; mi < 2; ++mi) {
                st[mi][ki] = __builtin_amdgcn_mfma_f32_16x16x32_bf16(
                    ak0, aq[mi][0], st[mi][ki], 0, 0, 0);
                st[mi][ki] = __builtin_amdgcn_mfma_f32_16x16x32_bf16(
                    ak1, aq[mi][1], st[mi][ki], 0, 0, 0);
            }
        }

        // online softmax: lane-local (16 vals) + 2 cross-quad shuffles
        s16x8 bp[2][4];
        #pragma unroll
        for (int mi = 0; mi < 2; ++mi) {
            float mx = st[mi][0][0];
            #pragma unroll
            for (int ki = 0; ki < 4; ++ki)
                #pragma unroll
                for (int r = 0; r < 4; ++r) mx = fmaxf(mx, st[mi][ki][r]);
            mx = fmaxf(mx, __shfl_xor(mx, 16));
            mx = fmaxf(mx, __shfl_xor(mx, 32));
            float mn = fmaxf(m_i[mi], mx);
            float alpha = __expf(m_i[mi] - mn);
            m_i[mi] = mn;
            #pragma unroll
            for (int ki = 0; ki < 4; ++ki) {
                s16x8 f = {};
                #pragma unroll
                for (int r = 0; r < 4; ++r)
                    f[r] = f2bf(__expf(st[mi][ki][r] - mn));
                bp[mi][ki] = f;                 // j<4 = P, j>=4 = 0
            }
            #pragma unroll
            for (int nd = 0; nd < 4; ++nd) oacc[mi][nd] *= alpha;
            lacc[mi] *= alpha;
        }

        // O += P·V ; l += P·1  (zero-padded k: key = quad*4 + j, j<4)
        #pragma unroll
        for (int ki = 0; ki < 4; ++ki) {
            #pragma unroll
            for (int nd = 0; nd < 4; ++nd) {
                int d = nd * 16 + l16;
                s16x4 v4 = *(const s16x4*)&Vs[d * 64
                             + ((ki * 2 + (quad >> 1)) ^ (l16 & 7)) * 8
                             + (quad & 1) * 4];
                s16x8 av = {v4[0], v4[1], v4[2], v4[3], 0, 0, 0, 0};
                #pragma unroll
                for (int mi = 0; mi < 2; ++mi)
                    oacc[mi][nd] = __builtin_amdgcn_mfma_f32_16x16x32_bf16(
                        av, bp[mi][ki], oacc[mi][nd], 0, 0, 0);
            }
            #pragma unroll
            for (int mi = 0; mi < 2; ++mi)
                lacc[mi] = __builtin_amdgcn_mfma_f32_16x16x32_bf16(
                    ones4, bp[mi][ki], lacc[mi], 0, 0, 0);
        }
    }

    // epilogue: lane holds row qrow=l16, d = nd*16+quad*4+r -> packed 8B stores
    const int b = bh >> 4, h = bh & 15;
    #pragma unroll
    for (int mi = 0; mi < 2; ++mi) {
        int srow = qb + w * 32 + mi * 16 + l16;
        float inv = 1.0f / lacc[mi][0];         // all regs identical = l[qrow]
        short* op = O + ((long)(b * SEQ + srow) * HDIM) + h * HD + quad * 4;
        #pragma unroll
        for (int nd = 0; nd < 4; ++nd) {
            s16x4 pk;
            #pragma unroll
            for (int r = 0; r < 4; ++r) pk[r] = f2bf(oacc[mi][nd][r] * inv);
            *(s16x4*)&op[nd * 16] = pk;
        }
    }
}

extern "C" void kernel_launch(void* const* d_in, const int* in_sizes, int n_in,
                              void* d_out, int out_size, void* d_ws, size_t ws_size,
                              hipStream_t stream) {
    const void* x_raw  = d_in[0];
    const void* Wq_raw = d_in[1];
    const void* Wp_raw = d_in[2];
    for (int i = 0; i < n_in; ++i) {
        if      (in_sizes[i] == 4096 * 1024) x_raw  = d_in[i];  // [2,2048,1024]
        else if (in_sizes[i] == 3072 * 1024) Wq_raw = d_in[i];  // [3072,1024]
        else if (in_sizes[i] == 1024 * 1024) Wp_raw = d_in[i];  // [1024,1024]
    }
    float* out = (float*)d_out;               // [2,2048,1024] f32 output

    const size_t MB = 1u << 20;
    char* ws = (char*)d_ws;
    short*  q    = (short*)(ws);              // [2,16,2048,64]  8 MB (pre-scaled 1/8)
    short*  k    = (short*)(ws +  8 * MB);    // [2,16,2048,64]  8 MB
    short*  vt   = (short*)(ws + 16 * MB);    // [2,16,64,2048]  8 MB (V^T)
    short*  xbf  = (short*)(ws + 24 * MB);    // [4096,1024]     8 MB (att reuses)
    short*  att  = xbf;                       // xbf consumed by gemm0 first
    short*  wqkv = (short*)(ws + 32 * MB);    // [3072,1024]     6 MB
    short*  wprj = (short*)(ws + 38 * MB);    // [1024,1024]     2 MB
    float2* tab  = (float2*)(ws + 40 * MB);   // [2048,32]       512 KB
    int*    flag = (int*)(ws + 40 * MB + 512 * 1024);

    detect_k<<<dim3(1), dim3(256), 0, stream>>>((const unsigned short*)x_raw, flag);

    cvt_all_k<<<dim3((XG4 + WQG4 + WPG4) / 256), dim3(256), 0, stream>>>(
        x_raw, Wq_raw, Wp_raw, xbf, wqkv, wprj, flag);

    rope_tab_k<<<dim3(SEQ * 32 / 256), dim3(256), 0, stream>>>(tab);

    gemm_bt<0><<<dim3(3072 / 128, 4096 / 128), dim3(256), 0, stream>>>(
        xbf, wqkv, q, k, vt, (float*)nullptr, tab, 1024, 3072);

    flash_attn<<<dim3(SEQ / 128, 2 * NHD), dim3(256), 0, stream>>>(q, k, vt, att);

    gemm_bt<1><<<dim3(1024 / 128, 4096 / 128), dim3(256), 0, stream>>>(
        att, wprj, (short*)nullptr, (short*)nullptr, (short*)nullptr, out, tab, 1024, 1024);
}

// Round 10
// 205.892 us; speedup vs baseline: 1.4301x; 1.0764x over previous
//
#include <hip/hip_runtime.h>
#include <math.h>

#define SEQ  2048
#define NHD  16
#define HD   64
#define HDIM 1024

typedef short s16x8 __attribute__((ext_vector_type(8)));   // 8 x bf16 (4 VGPRs)
typedef short s16x4 __attribute__((ext_vector_type(4)));
typedef float f32x4 __attribute__((ext_vector_type(4)));

typedef const __attribute__((address_space(1))) unsigned int* gp_t;
typedef __attribute__((address_space(3))) unsigned int* lp_t;

__device__ __forceinline__ void async16(const short* g, short* l) {
    // 16B per lane, LDS dest = wave-uniform base + lane*16 (no per-lane scatter)
    __builtin_amdgcn_global_load_lds((gp_t)g, (lp_t)l, 16, 0, 0);
}

__device__ __forceinline__ short f2bf(float f) {   // RNE f32 -> bf16 bits
    unsigned int u = __float_as_uint(f);
    u += 0x7fff + ((u >> 16) & 1);
    return (short)(u >> 16);
}
__device__ __forceinline__ float bf2f(short s) {
    return __uint_as_float(((unsigned int)(unsigned short)s) << 16);
}

// ---------------- input dtype detector (insurance) ---------------------------
__global__ void detect_k(const unsigned short* __restrict__ x, int* __restrict__ flag) {
    int cnt = 0;
    #pragma unroll 4
    for (int j = 0; j < 32; ++j) {
        unsigned short h = x[threadIdx.x * 32 + j];
        int e = (h >> 7) & 0xFF;
        cnt += (e >= 100 && e <= 140) ? 1 : 0;
    }
    __shared__ int tot;
    if (threadIdx.x == 0) tot = 0;
    __syncthreads();
    atomicAdd(&tot, cnt);
    __syncthreads();
    if (threadIdx.x == 0) *flag = (tot > (8192 * 9) / 10) ? 1 : 0;
}

// ---------------- fused convert: all 3 inputs -> canonical bf16 --------------
#define XG4  (4096 * 1024 / 4)
#define WQG4 (3072 * 1024 / 4)
#define WPG4 (1024 * 1024 / 4)
__global__ void cvt_all_k(const void* __restrict__ xr, const void* __restrict__ wqr,
                          const void* __restrict__ wpr, short* __restrict__ xo,
                          short* __restrict__ wqo, short* __restrict__ wpo,
                          const int* __restrict__ flag) {
    int i = blockIdx.x * 256 + threadIdx.x;
    const void* in; short* out; int j;
    if (i < XG4)             { in = xr;  out = xo;  j = i; }
    else if (i < XG4 + WQG4) { in = wqr; out = wqo; j = i - XG4; }
    else                     { in = wpr; out = wpo; j = i - XG4 - WQG4; }
    if (*flag) {
        ((s16x4*)out)[j] = ((const s16x4*)in)[j];
    } else {
        f32x4 v = ((const f32x4*)in)[j];
        s16x4 r;
        r[0] = f2bf(v[0]); r[1] = f2bf(v[1]);
        r[2] = f2bf(v[2]); r[3] = f2bf(v[3]);
        ((s16x4*)out)[j] = r;
    }
}

// ---------------- RoPE table: tab[s*32+d] = (cos, sin)(s * 10000^(-d/32)) ----
__global__ void rope_tab_k(float2* __restrict__ tab) {
    int i = blockIdx.x * 256 + threadIdx.x;
    if (i >= SEQ * 32) return;
    int s = i >> 5, d = i & 31;
    float invf = (float)pow(10000.0, -(double)d / 32.0);
    float af = (float)s * invf;               // replicate f32 freqs product
    double a = (double)af;
    tab[i] = make_float2((float)cos(a), (float)sin(a));
}

// ---------------- 128x128 bf16 MFMA GEMM, B given as [N,K] (B^T layout) ------
// LDS rows = 32 shorts = 4 x 16B chunks; chunk (r,c) stored at slot c^(r&3).
// MODE 0: qkv + RoPE epilogue -> q[b,h,s,d] (SCALED by 1/8), k, v^T[b,h,d,s]
// MODE 1: plain C[m,n] f32 write (final output dtype)
template<int MODE>
__global__ __launch_bounds__(256, 2)
void gemm_bt(const short* __restrict__ A, const short* __restrict__ B,
             short* __restrict__ q, short* __restrict__ kbuf, short* __restrict__ vt,
             float* __restrict__ C, const float2* __restrict__ tab,
             int K, int N) {
    __shared__ __align__(16) short As[128 * 32];
    __shared__ __align__(16) short Bs[128 * 32];
    const int tid  = threadIdx.x;
    const int w    = tid >> 6, lane = tid & 63;
    const int quad = lane >> 4, l16 = lane & 15;
    const int wm = (w >> 1) * 64, wn = (w & 1) * 64;
    const int rowA0 = blockIdx.y * 128;
    const int colB0 = blockIdx.x * 128;

    f32x4 acc[4][4] = {};

    for (int kb = 0; kb < K; kb += 32) {
        __syncthreads();
        #pragma unroll
        for (int i = 0; i < 2; ++i) {
            int cidx = i * 256 + w * 64 + lane;
            int row = cidx >> 2, sc = cidx & 3;
            int c = sc ^ (row & 3);           // XOR swizzle
            async16(&A[(long)(rowA0 + row) * K + kb + c * 8],
                    &As[(i * 256 + w * 64) * 8]);
            async16(&B[(long)(colB0 + row) * K + kb + c * 8],
                    &Bs[(i * 256 + w * 64) * 8]);
        }
        __syncthreads();

        s16x8 af[4], bfr[4];
        const int slot = quad ^ (l16 & 3);
        #pragma unroll
        for (int mi = 0; mi < 4; ++mi)
            af[mi] = *(const s16x8*)&As[(wm + mi * 16 + l16) * 32 + slot * 8];
        #pragma unroll
        for (int ni = 0; ni < 4; ++ni)
            bfr[ni] = *(const s16x8*)&Bs[(wn + ni * 16 + l16) * 32 + slot * 8];
        #pragma unroll
        for (int mi = 0; mi < 4; ++mi)
            #pragma unroll
            for (int ni = 0; ni < 4; ++ni)
                acc[mi][ni] = __builtin_amdgcn_mfma_f32_16x16x32_bf16(
                    af[mi], bfr[ni], acc[mi][ni], 0, 0, 0);
    }

    const int cb = colB0 + wn;                // wave's 64-col (one head) window
    if (MODE == 1) {
        #pragma unroll
        for (int mi = 0; mi < 4; ++mi) {
            #pragma unroll
            for (int r = 0; r < 4; ++r) {
                int gm = rowA0 + wm + mi * 16 + quad * 4 + r;
                float* cp = C + (long)gm * N + cb + l16;
                #pragma unroll
                for (int ni = 0; ni < 4; ++ni)
                    cp[ni * 16] = acc[mi][ni][r];
            }
        }
        return;
    }
    // MODE 0: qkv epilogue
    const int sector = cb >> 10;              // 0=q 1=k 2=v
    const int head   = (cb & 1023) >> 6;
    if (sector < 2) {
        const float sc = (sector == 0) ? 0.125f : 1.0f;  // fold 1/sqrt(64) into q
        #pragma unroll
        for (int mi = 0; mi < 4; ++mi) {
            #pragma unroll
            for (int r = 0; r < 4; ++r) {
                int gm = rowA0 + wm + mi * 16 + quad * 4 + r;
                int b = gm >> 11, s = gm & 2047;
                float v0 = acc[mi][0][r], v1 = acc[mi][1][r];
                float v2 = acc[mi][2][r], v3 = acc[mi][3][r];
                // RoPE on d<32: d0=l16, d1=l16+16; rot(d0)=-x[d0+16], rot(d1)=x[d1-16]
                float2 cs0 = tab[s * 32 + l16];
                float2 cs1 = tab[s * 32 + 16 + l16];
                float n0 = v0 * cs0.x - v1 * cs0.y;
                float n1 = v1 * cs1.x + v0 * cs1.y;
                short* dst = (sector == 0 ? q : kbuf)
                           + ((long)((b * NHD + head) * SEQ + s)) * HD + l16;
                dst[0]  = f2bf(n0 * sc);  dst[16] = f2bf(n1 * sc);
                dst[32] = f2bf(v2 * sc);  dst[48] = f2bf(v3 * sc);
            }
        }
    } else {
        // v stored transposed: vt[((b,h)*64+d)*SEQ + s]; pack r=0..3 (consec s)
        #pragma unroll
        for (int mi = 0; mi < 4; ++mi) {
            int srow = rowA0 + wm + mi * 16 + quad * 4;
            int b = srow >> 11, s0 = srow & 2047;
            #pragma unroll
            for (int ni = 0; ni < 4; ++ni) {
                s16x4 pk;
                #pragma unroll
                for (int r = 0; r < 4; ++r) pk[r] = f2bf(acc[mi][ni][r]);
                *(s16x4*)&vt[((long)((b * NHD + head) * HD + ni * 16 + l16)) * SEQ + s0] = pk;
            }
        }
    }
}

// ---------------- flash attention v4: S^T + packed PV + split-K=2 ------------
// S^T = K·Q^T. PV packs key-tiles (2t,2t+1) into ONE 16x16x32 (j<4 / j>=4).
// Each block handles 16 of 32 key tiles (blockIdx.z); partial (m,l,O-unnorm)
// written to opart/mlpart; merge_k combines. Grid 1024 -> 4 blocks/CU.
__global__ __launch_bounds__(256, 2)
void flash_attn(const short* __restrict__ Q, const short* __restrict__ K,
                const short* __restrict__ Vt, short* __restrict__ opart,
                float2* __restrict__ mlpart) {
    __shared__ __align__(16) short Qs[128 * 64];
    __shared__ __align__(16) short Ks[64 * 64];
    __shared__ __align__(16) short Vs[64 * 64];   // V^T: rows = d, cols = key
    const int tid  = threadIdx.x;
    const int w    = tid >> 6, lane = tid & 63;
    const int quad = lane >> 4, l16 = lane & 15;
    const int bh = blockIdx.y;
    const int qb = blockIdx.x * 128;
    const int z  = blockIdx.z;                  // key-split index (0,1)
    const short* Qp = Q  + (long)bh * SEQ * HD + (long)qb * HD;
    const short* Kp = K  + (long)bh * SEQ * HD;
    const short* Vp = Vt + (long)bh * HD * SEQ;

    #pragma unroll
    for (int i = 0; i < 4; ++i) {               // stage Q tile (128x64), swizzled
        int cidx = i * 256 + w * 64 + lane;
        int row = cidx >> 3, sc = cidx & 7;
        int c = sc ^ (row & 7);
        async16(&Qp[row * HD + c * 8], &Qs[(i * 256 + w * 64) * 8]);
    }
    __syncthreads();
    s16x8 aq[2][2];                             // B-operand: qrow=l16, k=quad*8+j
    #pragma unroll
    for (int mi = 0; mi < 2; ++mi)
        #pragma unroll
        for (int ks = 0; ks < 2; ++ks)
            aq[mi][ks] = *(const s16x8*)&Qs[(w * 32 + mi * 16 + l16) * 64
                                            + ((ks * 4 + quad) ^ (l16 & 7)) * 8];

    s16x8 ones8;
    #pragma unroll
    for (int j = 0; j < 8; ++j) ones8[j] = (short)0x3F80;  // bf16 1.0

    float m_i[2] = {-1e30f, -1e30f};            // lane-local: qrow = l16
    f32x4 oacc[2][4] = {};
    f32x4 lacc[2] = {};

    for (int kt = z * 16; kt < z * 16 + 16; ++kt) {
        __syncthreads();                        // prev-iter Ks/Vs readers done
        #pragma unroll
        for (int i = 0; i < 2; ++i) {
            int cidx = i * 256 + w * 64 + lane;
            int row = cidx >> 3, sc = cidx & 7;
            int c = sc ^ (row & 7);
            async16(&Kp[(kt * 64 + row) * HD + c * 8], &Ks[(i * 256 + w * 64) * 8]);
            async16(&Vp[(long)row * SEQ + kt * 64 + c * 8], &Vs[(i * 256 + w * 64) * 8]);
        }
        __syncthreads();

        // S^T = K·Q^T : st[mi][ki] = tile [key=ki*16+quad*4+r][qrow=l16]
        f32x4 st[2][4] = {};
        #pragma unroll
        for (int ki = 0; ki < 4; ++ki) {
            s16x8 ak0 = *(const s16x8*)&Ks[(ki * 16 + l16) * 64 + (quad ^ (l16 & 7)) * 8];
            s16x8 ak1 = *(const s16x8*)&Ks[(ki * 16 + l16) * 64 + ((4 + quad) ^ (l16 & 7)) * 8];
            #pragma unroll
            for (int mi = 0; mi < 2; ++mi) {
                st[mi][ki] = __builtin_amdgcn_mfma_f32_16x16x32_bf16(
                    ak0, aq[mi][0], st[mi][ki], 0, 0, 0);
                st[mi][ki] = __builtin_amdgcn_mfma_f32_16x16x32_bf16(
                    ak1, aq[mi][1], st[mi][ki], 0, 0, 0);
            }
        }

        // online softmax: lane-local + 2 cross-quad shuffles; pack P pairs:
        // bp[mi][t]: j<4 <- exp(st[2t]), j>=4 <- exp(st[2t+1]) (keys 32t+..)
        s16x8 bp[2][2];
        #pragma unroll
        for (int mi = 0; mi < 2; ++mi) {
            float mx = st[mi][0][0];
            #pragma unroll
            for (int ki = 0; ki < 4; ++ki)
                #pragma unroll
                for (int r = 0; r < 4; ++r) mx = fmaxf(mx, st[mi][ki][r]);
            mx = fmaxf(mx, __shfl_xor(mx, 16));
            mx = fmaxf(mx, __shfl_xor(mx, 32));
            float mn = fmaxf(m_i[mi], mx);
            float alpha = __expf(m_i[mi] - mn);
            m_i[mi] = mn;
            #pragma unroll
            for (int t = 0; t < 2; ++t) {
                s16x8 f;
                #pragma unroll
                for (int r = 0; r < 4; ++r) {
                    f[r]     = f2bf(__expf(st[mi][2 * t][r] - mn));
                    f[4 + r] = f2bf(__expf(st[mi][2 * t + 1][r] - mn));
                }
                bp[mi][t] = f;
            }
            #pragma unroll
            for (int nd = 0; nd < 4; ++nd) oacc[mi][nd] *= alpha;
            lacc[mi] *= alpha;
        }

        // O += P·V ; l += P·1  (virtual k: j<4 -> key 32t+quad*4+j,
        //                                  j>=4 -> key 32t+16+quad*4+j-4)
        #pragma unroll
        for (int t = 0; t < 2; ++t) {
            #pragma unroll
            for (int nd = 0; nd < 4; ++nd) {
                int d = nd * 16 + l16;
                s16x4 va = *(const s16x4*)&Vs[d * 64
                             + ((4 * t + (quad >> 1)) ^ (l16 & 7)) * 8
                             + (quad & 1) * 4];
                s16x4 vb = *(const s16x4*)&Vs[d * 64
                             + ((4 * t + 2 + (quad >> 1)) ^ (l16 & 7)) * 8
                             + (quad & 1) * 4];
                s16x8 av = {va[0], va[1], va[2], va[3],
                            vb[0], vb[1], vb[2], vb[3]};
                #pragma unroll
                for (int mi = 0; mi < 2; ++mi)
                    oacc[mi][nd] = __builtin_amdgcn_mfma_f32_16x16x32_bf16(
                        av, bp[mi][t], oacc[mi][nd], 0, 0, 0);
            }
            #pragma unroll
            for (int mi = 0; mi < 2; ++mi)
                lacc[mi] = __builtin_amdgcn_mfma_f32_16x16x32_bf16(
                    ones8, bp[mi][t], lacc[mi], 0, 0, 0);
        }
    }

    // partial store: unnormalized O (bf16) + (m, l) per row
    #pragma unroll
    for (int mi = 0; mi < 2; ++mi) {
        int srow = qb + w * 32 + mi * 16 + l16;
        long prow = (long)(z * 32 + bh) * SEQ + srow;
        if (quad == 0) mlpart[prow] = make_float2(m_i[mi], lacc[mi][0]);
        short* op = opart + prow * 64 + quad * 4;
        #pragma unroll
        for (int nd = 0; nd < 4; ++nd) {
            s16x4 pk;
            #pragma unroll
            for (int r = 0; r < 4; ++r) pk[r] = f2bf(oacc[mi][nd][r]);
            *(s16x4*)&op[nd * 16] = pk;
        }
    }
}

// ---------------- merge the two key-split partials -> att --------------------
__global__ __launch_bounds__(256)
void merge_k(const short* __restrict__ opart, const float2* __restrict__ mlpart,
             short* __restrict__ att) {
    int idx = blockIdx.x * 256 + threadIdx.x;     // 65536 rows x 16 thr/row
    int t16 = idx & 15, rowg = idx >> 4;
    int bh = rowg >> 11, srow = rowg & 2047;
    float2 ml1 = mlpart[rowg];
    float2 ml2 = mlpart[65536 + rowg];
    float m  = fmaxf(ml1.x, ml2.x);
    float w1 = __expf(ml1.x - m), w2 = __expf(ml2.x - m);
    float inv = 1.0f / (w1 * ml1.y + w2 * ml2.y);
    w1 *= inv; w2 *= inv;
    s16x4 o1 = *(const s16x4*)&opart[(long)rowg * 64 + t16 * 4];
    s16x4 o2 = *(const s16x4*)&opart[(long)(65536 + rowg) * 64 + t16 * 4];
    int b = bh >> 4, h = bh & 15;
    short* dst = att + ((long)(b * SEQ + srow)) * HDIM + h * HD + t16 * 4;
    s16x4 r;
    #pragma unroll
    for (int j = 0; j < 4; ++j)
        r[j] = f2bf(w1 * bf2f(o1[j]) + w2 * bf2f(o2[j]));
    *(s16x4*)dst = r;
}

extern "C" void kernel_launch(void* const* d_in, const int* in_sizes, int n_in,
                              void* d_out, int out_size, void* d_ws, size_t ws_size,
                              hipStream_t stream) {
    const void* x_raw  = d_in[0];
    const void* Wq_raw = d_in[1];
    const void* Wp_raw = d_in[2];
    for (int i = 0; i < n_in; ++i) {
        if      (in_sizes[i] == 4096 * 1024) x_raw  = d_in[i];  // [2,2048,1024]
        else if (in_sizes[i] == 3072 * 1024) Wq_raw = d_in[i];  // [3072,1024]
        else if (in_sizes[i] == 1024 * 1024) Wp_raw = d_in[i];  // [1024,1024]
    }
    float* out = (float*)d_out;               // [2,2048,1024] f32 output

    const size_t MB = 1u << 20;
    char* ws = (char*)d_ws;
    short*  q     = (short*)(ws);             // [2,16,2048,64]  8 MB (pre-scaled 1/8)
    short*  k     = (short*)(ws +  8 * MB);   // [2,16,2048,64]  8 MB
    short*  vt    = (short*)(ws + 16 * MB);   // [2,16,64,2048]  8 MB (V^T)
    short*  xbf   = (short*)(ws + 24 * MB);   // [4096,1024]     8 MB (att reuses)
    short*  att   = xbf;                      // xbf consumed by gemm0 first
    short*  wqkv  = (short*)(ws + 32 * MB);   // [3072,1024]     6 MB
    short*  wprj  = (short*)(ws + 38 * MB);   // [1024,1024]     2 MB
    float2* tab   = (float2*)(ws + 40 * MB);  // [2048,32]       512 KB
    int*    flag  = (int*)(ws + 40 * MB + 512 * 1024);
    short*  opart = (short*)(ws + 41 * MB);   // [2,32,2048,64] 16 MB bf16
    float2* mlprt = (float2*)(ws + 57 * MB);  // [2,32,2048]     1 MB

    detect_k<<<dim3(1), dim3(256), 0, stream>>>((const unsigned short*)x_raw, flag);

    cvt_all_k<<<dim3((XG4 + WQG4 + WPG4) / 256), dim3(256), 0, stream>>>(
        x_raw, Wq_raw, Wp_raw, xbf, wqkv, wprj, flag);

    rope_tab_k<<<dim3(SEQ * 32 / 256), dim3(256), 0, stream>>>(tab);

    gemm_bt<0><<<dim3(3072 / 128, 4096 / 128), dim3(256), 0, stream>>>(
        xbf, wqkv, q, k, vt, (float*)nullptr, tab, 1024, 3072);

    flash_attn<<<dim3(SEQ / 128, 2 * NHD, 2), dim3(256), 0, stream>>>(
        q, k, vt, opart, mlprt);

    merge_k<<<dim3(65536 * 16 / 256), dim3(256), 0, stream>>>(opart, mlprt, att);

    gemm_bt<1><<<dim3(1024 / 128, 4096 / 128), dim3(256), 0, stream>>>(
        att, wprj, (short*)nullptr, (short*)nullptr, (short*)nullptr, out, tab, 1024, 1024);
}